// Round 7
// baseline (558.443 us; speedup 1.0000x reference)
//
#include <hip/hip_runtime.h>
#include <stdint.h>

// Attention block: out = (softmax((x Wq^T + bq)(x Wk^T + bk)^T / sqrt(128)) (x Wv^T + bv)) Wo^T + bo + x
// N=8192, D=1024. bf16 MFMA GEMMs. Big GEMMs (S, PV): 4-phase interleaved schedule
// (T3+T4+T5): per-phase {stage-issue, ds_read quadrant, barrier, setprio+MFMA, barrier},
// counted vmcnt only at phase 3. Small GEMMs: verified 2-phase pipeline (round 6).

#define NTOK 8192
#define DMOD 1024
static constexpr float INV_SCALE = 0.08838834764831845f; // 1/sqrt(128)

typedef __attribute__((ext_vector_type(8))) short short8;   // 8 bf16 MFMA fragment
typedef __attribute__((ext_vector_type(4))) float f32x4;
typedef __attribute__((ext_vector_type(8))) unsigned short u16x8;
typedef __attribute__((ext_vector_type(4))) unsigned short u16x4;

__device__ __forceinline__ unsigned short f2bf(float f) {
  union { float f; uint32_t u; } x{f};
  uint32_t r = x.u + 0x7fffu + ((x.u >> 16) & 1u);
  return (unsigned short)(r >> 16);
}
__device__ __forceinline__ float bf2f(unsigned short b) {
  return __uint_as_float(((uint32_t)b) << 16);
}
__device__ __forceinline__ void async16(void* lds, const void* g) {
  __builtin_amdgcn_global_load_lds((const __attribute__((address_space(1))) void*)g,
                                   (__attribute__((address_space(3))) void*)lds, 16, 0, 0);
}
template<int N> __device__ __forceinline__ void waitvm() {
  if constexpr (N == 0) asm volatile("s_waitcnt vmcnt(0)" ::: "memory");
  else if constexpr (N == 3) asm volatile("s_waitcnt vmcnt(3)" ::: "memory");
  else if constexpr (N == 4) asm volatile("s_waitcnt vmcnt(4)" ::: "memory");
  else if constexpr (N == 6) asm volatile("s_waitcnt vmcnt(6)" ::: "memory");
  else if constexpr (N == 8) asm volatile("s_waitcnt vmcnt(8)" ::: "memory");
  else static_assert(N == 0, "unsupported vmcnt");
}

// ---------------- cast f32 -> bf16 ----------------
__global__ __launch_bounds__(256) void cast_f32_bf16(const float* __restrict__ in,
                                                     unsigned short* __restrict__ out, int n4) {
  int i = blockIdx.x * 256 + threadIdx.x;
  int stride = gridDim.x * 256;
  for (; i < n4; i += stride) {
    float4 v = ((const float4*)in)[i];
    u16x4 o;
    o[0] = f2bf(v.x); o[1] = f2bf(v.y); o[2] = f2bf(v.z); o[3] = f2bf(v.w);
    ((u16x4*)out)[i] = o;
  }
}

// ======== 4-phase interleaved GEMM (T3+T4+T5): C = A (MxK) * B^T (B NxK) ========
// BK=32, 4 LDS buffers, prefetch distance 3, tile t+3's L loads spread over phases.
// Phase p computes output quadrant (p>>1, p&1); reads: p0 = a-low+b-low, p1 = b-high,
// p2 = a-high. vmcnt(2L) at phase 3 => tile t+1 landed before iter t+1 reads.
template<int BM, int BN, int WM, int WN, bool BIAS, bool TRANS, bool F32OUT, bool RES>
__global__ __launch_bounds__(WM*WN*64, 2) void gemm_8ph(
    const unsigned short* __restrict__ A, const unsigned short* __restrict__ B,
    unsigned short* __restrict__ O16, float* __restrict__ O32,
    const float* __restrict__ bias, const float* __restrict__ resid,
    int M, int N, int K, float scale)
{
  constexpr int THREADS = WM * WN * 64;
  constexpr int M_REP = BM / (WM * 16);
  constexpr int N_REP = BN / (WN * 16);
  constexpr int M2 = M_REP / 2, N2 = N_REP / 2;
  constexpr int ABYTES = BM * 64;          // 32 bf16 = 64 B per row
  constexpr int BBYTES = BN * 64;
  constexpr int BUFB = ABYTES + BBYTES;
  constexpr int LOADS = BUFB / (THREADS * 16);
  static_assert(M_REP >= 2 && N_REP >= 2 && (M_REP % 2 == 0) && (N_REP % 2 == 0));
  static_assert(LOADS >= 1 && LOADS <= 4);
  static_assert(ABYTES % (THREADS * 16) == 0, "A/B staging regions align to load boundary");

  __shared__ alignas(16) char lds[4 * BUFB];

  const int t = threadIdx.x;
  const int l = t & 63, w = t >> 6;
  const int wrow = (w / WN) * (M_REP * 16);
  const int wcol = (w % WN) * (N_REP * 16);

  // bijective XCD swizzle (m204)
  const int nwg = gridDim.x * gridDim.y;
  const int flat = blockIdx.y * gridDim.x + blockIdx.x;
  const int q8 = nwg >> 3, r8 = nwg & 7;
  const int xcd = flat & 7, pos = flat >> 3;
  const int swz = (xcd < r8 ? xcd * (q8 + 1) : r8 * (q8 + 1) + (xcd - r8) * q8) + pos;
  const int row0 = (swz / gridDim.x) * BM;
  const int col0 = (swz % gridDim.x) * BN;

  // staging: load li covers LDS bytes [li*THREADS*16 + t*16 ..+16). Source column
  // pre-swizzled (slot ^ ((row>>1)&3)) so swizzled READ returns logical data.
  const unsigned short* gsrc[LOADS];
  int ldst[LOADS];
#pragma unroll
  for (int li = 0; li < LOADS; ++li) {
    const int byte0 = li * THREADS * 16 + t * 16;
    int r; const unsigned short* base;
    if (byte0 < ABYTES) { r = byte0 >> 6; base = A + (size_t)(row0 + r) * K; }
    else { r = (byte0 - ABYTES) >> 6; base = B + (size_t)(col0 + r) * K; }
    const int slot = (byte0 >> 4) & 3;
    gsrc[li] = base + (slot ^ ((r >> 1) & 3)) * 8;
    ldst[li] = byte0;
  }

  // fragment read offsets: row r, logical slot l>>4 -> stored slot ^((r>>1)&3)
  int offA[M_REP], offB[N_REP];
#pragma unroll
  for (int m = 0; m < M_REP; ++m) {
    int r = wrow + m * 16 + (l & 15);
    offA[m] = r * 64 + (((l >> 4) ^ ((r >> 1) & 3)) * 16);
  }
#pragma unroll
  for (int n = 0; n < N_REP; ++n) {
    int r = wcol + n * 16 + (l & 15);
    offB[n] = ABYTES + r * 64 + (((l >> 4) ^ ((r >> 1) & 3)) * 16);
  }

  f32x4 acc[M_REP][N_REP] = {};
  const int KT = K / 32;

  // prologue: stage tiles 0,1,2 into bufs 0,1,2
#pragma unroll
  for (int j = 0; j < 3; ++j) {
    char* bb = lds + j * BUFB;
#pragma unroll
    for (int li = 0; li < LOADS; ++li) async16(bb + ldst[li], gsrc[li] + j * 32);
  }
  waitvm<2 * LOADS>();              // tile 0 landed (tiles 1,2 in flight)
  __builtin_amdgcn_s_barrier();

  for (int t3 = 0; t3 < KT; ++t3) {
    const char* rb = lds + (t3 & 3) * BUFB;
    char* sb = lds + ((t3 + 3) & 3) * BUFB;
    const bool st = (t3 + 3) < KT;
    short8 a[M_REP], b[N_REP];
#pragma unroll
    for (int p = 0; p < 4; ++p) {
      if (p < LOADS && st) async16(sb + ldst[p], gsrc[p] + (size_t)(t3 + 3) * 32);
      if (p == 0) {
#pragma unroll
        for (int m = 0; m < M2; ++m) a[m] = *(const short8*)(rb + offA[m]);
#pragma unroll
        for (int n = 0; n < N2; ++n) b[n] = *(const short8*)(rb + offB[n]);
      } else if (p == 1) {
#pragma unroll
        for (int n = N2; n < N_REP; ++n) b[n] = *(const short8*)(rb + offB[n]);
      } else if (p == 2) {
#pragma unroll
        for (int m = M2; m < M_REP; ++m) a[m] = *(const short8*)(rb + offA[m]);
      }
      __builtin_amdgcn_s_barrier();          // phase-aligned: reads issued everywhere
      __builtin_amdgcn_s_setprio(1);
      const int mh = (p >> 1) * M2, nh = (p & 1) * N2;
#pragma unroll
      for (int m = 0; m < M2; ++m)
#pragma unroll
        for (int n = 0; n < N2; ++n)
          acc[mh + m][nh + n] =
              __builtin_amdgcn_mfma_f32_16x16x32_bf16(a[mh + m], b[nh + n], acc[mh + m][nh + n], 0, 0, 0);
      __builtin_amdgcn_s_setprio(0);
      if (p == 3) {                          // counted wait, once per K-step (T4)
        if (st) waitvm<2 * LOADS>();
        else if (t3 + 2 < KT) waitvm<LOADS>();
        else waitvm<0>();
      }
      __builtin_amdgcn_s_barrier();          // tile boundary safety
    }
  }

  // epilogue. C/D layout: col = lane&15, row = (lane>>4)*4 + j
  const int rr = (l >> 4) * 4;
#pragma unroll
  for (int m = 0; m < M_REP; ++m) {
#pragma unroll
    for (int n = 0; n < N_REP; ++n) {
#pragma unroll
      for (int j = 0; j < 4; ++j) {
        int r = row0 + wrow + m * 16 + rr + j;
        int c = col0 + wcol + n * 16 + (l & 15);
        float v = acc[m][n][j];
        if (BIAS) v += bias[c];
        v *= scale;
        if (RES) v += resid[(size_t)r * N + c];
        if (F32OUT) O32[(size_t)r * N + c] = v;
        else if (TRANS) O16[(size_t)c * M + r] = f2bf(v);
        else O16[(size_t)r * N + c] = f2bf(v);
      }
    }
  }
}

// ======== 2-phase pipelined GEMM (round-6 verified) for the small projections ========
template<int BM, int BN, int WM, int WN, bool BIAS, bool TRANS, bool F32OUT, bool RES>
__global__ __launch_bounds__(WM*WN*64, 2) void gemm_pipe(
    const unsigned short* __restrict__ A, const unsigned short* __restrict__ B,
    unsigned short* __restrict__ O16, float* __restrict__ O32,
    const float* __restrict__ bias, const float* __restrict__ resid,
    int M, int N, int K, float scale)
{
  constexpr int THREADS = WM * WN * 64;
  constexpr int M_REP = BM / (WM * 16);
  constexpr int N_REP = BN / (WN * 16);
  constexpr int ABYTES = BM * 64;
  constexpr int BBYTES = BN * 64;
  constexpr int BUFB = ABYTES + BBYTES;
  constexpr int RPR = THREADS / 4;
  static_assert(BM == BN, "square tiles only");
  static_assert(BM * 64 == RPR * 64 * 2, "2 staging rounds per operand");

  __shared__ alignas(16) char lds[4 * BUFB];

  const int t = threadIdx.x;
  const int l = t & 63, w = t >> 6;
  const int wrow = (w / WN) * (M_REP * 16);
  const int wcol = (w % WN) * (N_REP * 16);

  const int nwg = gridDim.x * gridDim.y;
  const int flat = blockIdx.y * gridDim.x + blockIdx.x;
  const int q8 = nwg >> 3, r8 = nwg & 7;
  const int xcd = flat & 7, pos = flat >> 3;
  const int swz = (xcd < r8 ? xcd * (q8 + 1) : r8 * (q8 + 1) + (xcd - r8) * q8) + pos;
  const int row0 = (swz / gridDim.x) * BM;
  const int col0 = (swz % gridDim.x) * BN;

  const int sr0 = t >> 2, sr1 = (t >> 2) + RPR;
  const int c0 = ((t & 3) ^ ((sr0 >> 1) & 3)) * 8;
  const int c1 = ((t & 3) ^ ((sr1 >> 1) & 3)) * 8;
  const unsigned short* gsrc[4];
  int ldst[4];
  gsrc[0] = A + (size_t)(row0 + sr0) * K + c0;  ldst[0] = t * 16;
  gsrc[1] = A + (size_t)(row0 + sr1) * K + c1;  ldst[1] = t * 16 + RPR * 64;
  gsrc[2] = B + (size_t)(col0 + sr0) * K + c0;  ldst[2] = ABYTES + t * 16;
  gsrc[3] = B + (size_t)(col0 + sr1) * K + c1;  ldst[3] = ABYTES + t * 16 + RPR * 64;

  int offA[M_REP], offB[N_REP];
#pragma unroll
  for (int m = 0; m < M_REP; ++m) {
    int r = wrow + m * 16 + (l & 15);
    offA[m] = r * 64 + (((l >> 4) ^ ((r >> 1) & 3)) * 16);
  }
#pragma unroll
  for (int n = 0; n < N_REP; ++n) {
    int r = wcol + n * 16 + (l & 15);
    offB[n] = ABYTES + r * 64 + (((l >> 4) ^ ((r >> 1) & 3)) * 16);
  }

  f32x4 acc[M_REP][N_REP] = {};
  const int KT = K / 32;

#pragma unroll
  for (int j = 0; j < 3; ++j) {
    char* bb = lds + j * BUFB;
#pragma unroll
    for (int s = 0; s < 4; ++s) async16(bb + ldst[s], gsrc[s] + j * 32);
  }

  for (int t3 = 0; t3 < KT; ++t3) {
    asm volatile("s_waitcnt lgkmcnt(0)" ::: "memory");
    __builtin_amdgcn_s_barrier();
    asm volatile("" ::: "memory");
    if (t3 + 3 < KT) {
      char* bb = lds + ((t3 + 3) & 3) * BUFB;
#pragma unroll
      for (int s = 0; s < 4; ++s) async16(bb + ldst[s], gsrc[s] + (size_t)(t3 + 3) * 32);
      asm volatile("s_waitcnt vmcnt(12)" ::: "memory");
    } else if (t3 + 3 == KT) {
      asm volatile("s_waitcnt vmcnt(8)" ::: "memory");
    } else if (t3 + 2 == KT) {
      asm volatile("s_waitcnt vmcnt(4)" ::: "memory");
    } else {
      asm volatile("s_waitcnt vmcnt(0)" ::: "memory");
    }
    __builtin_amdgcn_s_barrier();
    asm volatile("" ::: "memory");

    const char* bb = lds + (t3 & 3) * BUFB;
    short8 af[M_REP], bf[N_REP];
#pragma unroll
    for (int m = 0; m < M_REP; ++m) af[m] = *(const short8*)(bb + offA[m]);
#pragma unroll
    for (int n = 0; n < N_REP; ++n) bf[n] = *(const short8*)(bb + offB[n]);
#pragma unroll
    for (int m = 0; m < M_REP; ++m)
#pragma unroll
      for (int n = 0; n < N_REP; ++n)
        acc[m][n] = __builtin_amdgcn_mfma_f32_16x16x32_bf16(af[m], bf[n], acc[m][n], 0, 0, 0);
  }

  const int rr = (l >> 4) * 4;
#pragma unroll
  for (int m = 0; m < M_REP; ++m) {
#pragma unroll
    for (int n = 0; n < N_REP; ++n) {
#pragma unroll
      for (int j = 0; j < 4; ++j) {
        int r = row0 + wrow + m * 16 + rr + j;
        int c = col0 + wcol + n * 16 + (l & 15);
        float v = acc[m][n][j];
        if (BIAS) v += bias[c];
        v *= scale;
        if (RES) v += resid[(size_t)r * N + c];
        if (F32OUT) O32[(size_t)r * N + c] = v;
        else if (TRANS) O16[(size_t)c * M + r] = f2bf(v);
        else O16[(size_t)r * N + c] = f2bf(v);
      }
    }
  }
}

// ---------------- row softmax in-place on bf16 [8192 x 8192] ----------------
__global__ __launch_bounds__(256) void softmax_inplace(unsigned short* __restrict__ S) {
  __shared__ float red[8];
  const int t = threadIdx.x;
  unsigned short* rp = S + (size_t)blockIdx.x * NTOK;
  float v[32];
#pragma unroll
  for (int i = 0; i < 4; ++i) {
    u16x8 u = ((const u16x8*)rp)[t + i * 256];
#pragma unroll
    for (int j = 0; j < 8; ++j) v[i * 8 + j] = bf2f(u[j]);
  }
  float m = -1e30f;
#pragma unroll
  for (int k = 0; k < 32; ++k) m = fmaxf(m, v[k]);
#pragma unroll
  for (int o = 32; o; o >>= 1) m = fmaxf(m, __shfl_xor(m, o));
  if ((t & 63) == 0) red[t >> 6] = m;
  __syncthreads();
  m = fmaxf(fmaxf(red[0], red[1]), fmaxf(red[2], red[3]));
  float s = 0.f;
#pragma unroll
  for (int k = 0; k < 32; ++k) { v[k] = __expf(v[k] - m); s += v[k]; }
#pragma unroll
  for (int o = 32; o; o >>= 1) s += __shfl_xor(s, o);
  if ((t & 63) == 0) red[4 + (t >> 6)] = s;
  __syncthreads();
  s = red[4] + red[5] + red[6] + red[7];
  float inv = 1.0f / s;
#pragma unroll
  for (int i = 0; i < 4; ++i) {
    u16x8 u;
#pragma unroll
    for (int j = 0; j < 8; ++j) u[j] = f2bf(v[i * 8 + j] * inv);
    ((u16x8*)rp)[t + i * 256] = u;
  }
}

extern "C" void kernel_launch(void* const* d_in, const int* in_sizes, int n_in,
                              void* d_out, int out_size, void* d_ws, size_t ws_size,
                              hipStream_t stream) {
  const float* x  = (const float*)d_in[0];
  const float* Wq = (const float*)d_in[1];
  const float* bq = (const float*)d_in[2];
  const float* Wk = (const float*)d_in[3];
  const float* bk = (const float*)d_in[4];
  const float* Wv = (const float*)d_in[5];
  const float* bv = (const float*)d_in[6];
  const float* Wo = (const float*)d_in[7];
  const float* bo = (const float*)d_in[8];
  float* out = (float*)d_out;

  char* p = (char*)d_ws;
  unsigned short* xb  = (unsigned short*)p; p += (size_t)NTOK * DMOD * 2;   // 16 MB
  unsigned short* Wqb = (unsigned short*)p; p += (size_t)DMOD * DMOD * 2;   // 2 MB
  unsigned short* Wkb = (unsigned short*)p; p += (size_t)DMOD * DMOD * 2;
  unsigned short* Wvb = (unsigned short*)p; p += (size_t)DMOD * DMOD * 2;
  unsigned short* Wob = (unsigned short*)p; p += (size_t)DMOD * DMOD * 2;
  unsigned short* Qb  = (unsigned short*)p; p += (size_t)NTOK * DMOD * 2;
  unsigned short* Kb  = (unsigned short*)p; p += (size_t)NTOK * DMOD * 2;
  unsigned short* Vt  = (unsigned short*)p; p += (size_t)DMOD * NTOK * 2;   // V transposed [D][N]
  unsigned short* Ob  = (unsigned short*)p; p += (size_t)NTOK * DMOD * 2;
  unsigned short* S   = (unsigned short*)p; p += (size_t)NTOK * NTOK * 2;   // 128 MB

  cast_f32_bf16<<<dim3(2048), dim3(256), 0, stream>>>(x, xb, NTOK * DMOD / 4);
  cast_f32_bf16<<<dim3(1024), dim3(256), 0, stream>>>(Wq, Wqb, DMOD * DMOD / 4);
  cast_f32_bf16<<<dim3(1024), dim3(256), 0, stream>>>(Wk, Wkb, DMOD * DMOD / 4);
  cast_f32_bf16<<<dim3(1024), dim3(256), 0, stream>>>(Wv, Wvb, DMOD * DMOD / 4);
  cast_f32_bf16<<<dim3(1024), dim3(256), 0, stream>>>(Wo, Wob, DMOD * DMOD / 4);

  dim3 b512(512), b256(256);
  dim3 gS(NTOK / 256, NTOK / 256);      // (32, 32)
  dim3 gProj(DMOD / 128, NTOK / 128);   // (8, 64)
  dim3 gPV(DMOD / 128, NTOK / 256);     // (8, 32) for 256x128 tile

  // Q = (x Wq^T + bq) / sqrt(128)
  gemm_pipe<128,128,2,2,true,false,false,false><<<gProj, b256, 0, stream>>>(xb, Wqb, Qb, nullptr, bq, nullptr, NTOK, DMOD, DMOD, INV_SCALE);
  // K = x Wk^T + bk
  gemm_pipe<128,128,2,2,true,false,false,false><<<gProj, b256, 0, stream>>>(xb, Wkb, Kb, nullptr, bk, nullptr, NTOK, DMOD, DMOD, 1.0f);
  // V^T = (x Wv^T + bv)^T   [D,N]
  gemm_pipe<128,128,2,2,true,true,false,false><<<gProj, b256, 0, stream>>>(xb, Wvb, Vt, nullptr, bv, nullptr, NTOK, DMOD, DMOD, 1.0f);
  // S = Q K^T (scale folded into Q)  [N,N], 256^2 tile, 4-phase schedule
  gemm_8ph<256,256,2,4,false,false,false,false><<<gS, b512, 0, stream>>>(Qb, Kb, S, nullptr, nullptr, nullptr, NTOK, NTOK, DMOD, 1.0f);
  // softmax rows in-place
  softmax_inplace<<<dim3(NTOK), b256, 0, stream>>>(S);
  // O = att V = att (Vt)^T  [N,D], 256x128 tile, 4-phase schedule
  gemm_8ph<256,128,4,2,false,false,false,false><<<gPV, b512, 0, stream>>>(S, Vt, Ob, nullptr, nullptr, nullptr, NTOK, DMOD, NTOK, 1.0f);
  // out = O Wo^T + bo + x  fp32
  gemm_pipe<128,128,2,2,true,false,true,true><<<gProj, b256, 0, stream>>>(Ob, Wob, nullptr, out, bo, x, NTOK, DMOD, DMOD, 1.0f);
}